// Round 6
// baseline (682.360 us; speedup 1.0000x reference)
//
#include <hip/hip_runtime.h>
#include <stdint.h>

#define NN 8192
#define FIN 512
#define FOUT 256
#define ALPHA 0.2f
#define KSPLIT 4
#define JT 32
#define IT 32
#define NT ((NN / KSPLIT) / JT)   // 64 iterations per block

typedef float f32x4 __attribute__((ext_vector_type(4)));
typedef short s16x8 __attribute__((ext_vector_type(8)));

__device__ __forceinline__ uint16_t f2bf(float f) {
  union { float f; uint32_t u; } v; v.f = f;
  uint32_t u = v.u + 0x7fffu + ((v.u >> 16) & 1u);
  return (uint16_t)(u >> 16);
}

// ---------------- 1. wa1/wa2 = W @ a1 / a2 (fp32) ----------------
__global__ __launch_bounds__(256) void k_wa(const float* __restrict__ W,
                                            const float* __restrict__ a,
                                            float* __restrict__ wa1, float* __restrict__ wa2) {
  __shared__ float a1[256], a2[256];
  int tid = threadIdx.x;
  a1[tid] = a[tid];
  a2[tid] = a[tid + 256];
  __syncthreads();
  int m = blockIdx.x * 256 + tid;   // 0..511
  const float* wrow = W + (size_t)m * FOUT;
  float s1 = 0.f, s2 = 0.f;
  for (int k = 0; k < FOUT; k += 4) {
    f32x4 v = *(const f32x4*)(wrow + k);
#pragma unroll
    for (int i = 0; i < 4; i++) {
      s1 += v[i] * a1[k + i];
      s2 += v[i] * a2[k + i];
    }
  }
  wa1[m] = s1; wa2[m] = s2;
}

// ---------------- 2. f1/f2 = x @ wa1/wa2 + x->bf16 + l_arr zero ----------------
__global__ __launch_bounds__(256) void k_f1f2(const float* __restrict__ x,
                                              const float* __restrict__ wa1,
                                              const float* __restrict__ wa2,
                                              float* __restrict__ f1, float* __restrict__ f2,
                                              uint16_t* __restrict__ xb,
                                              float* __restrict__ l_arr) {
  __shared__ float s1[512], s2[512];
  int tid = threadIdx.x;
  if (tid < 4) l_arr[blockIdx.x * 4 + tid] = 0.f;
  s1[tid] = wa1[tid]; s1[tid + 256] = wa1[tid + 256];
  s2[tid] = wa2[tid]; s2[tid + 256] = wa2[tid + 256];
  __syncthreads();
  int w = tid >> 6, l = tid & 63;
  int row = blockIdx.x * 4 + w;
  const float* xr = x + (size_t)row * FIN + l * 8;
  f32x4 v0 = *(const f32x4*)xr;
  f32x4 v1 = *(const f32x4*)(xr + 4);
  uint4 pk;
  pk.x = (uint32_t)f2bf(v0[0]) | ((uint32_t)f2bf(v0[1]) << 16);
  pk.y = (uint32_t)f2bf(v0[2]) | ((uint32_t)f2bf(v0[3]) << 16);
  pk.z = (uint32_t)f2bf(v1[0]) | ((uint32_t)f2bf(v1[1]) << 16);
  pk.w = (uint32_t)f2bf(v1[2]) | ((uint32_t)f2bf(v1[3]) << 16);
  *(uint4*)(xb + (size_t)row * FIN + l * 8) = pk;
  int kb = l * 8;
  float d1 = 0.f, d2 = 0.f;
#pragma unroll
  for (int i = 0; i < 4; i++) {
    d1 += v0[i] * s1[kb + i] + v1[i] * s1[kb + 4 + i];
    d2 += v0[i] * s2[kb + i] + v1[i] * s2[kb + 4 + i];
  }
#pragma unroll
  for (int off = 32; off; off >>= 1) {
    d1 += __shfl_down(d1, off);
    d2 += __shfl_down(d2, off);
  }
  if (l == 0) { f1[row] = d1; f2[row] = d2; }
}

// ---------------- 3. wt[f][k] = bf16(W[k][f]) ----------------
__global__ __launch_bounds__(256) void k_prep_wt(const float* __restrict__ W,
                                                 uint16_t* __restrict__ wt) {
  int idx = blockIdx.x * 256 + threadIdx.x;
  int f  = idx >> 7;
  int k4 = (idx & 127) * 4;
  ushort4 o;
  o.x = f2bf(W[(size_t)(k4 + 0) * FOUT + f]);
  o.y = f2bf(W[(size_t)(k4 + 1) * FOUT + f]);
  o.z = f2bf(W[(size_t)(k4 + 2) * FOUT + f]);
  o.w = f2bf(W[(size_t)(k4 + 3) * FOUT + f]);
  *(ushort4*)(wt + (size_t)f * FIN + k4) = o;
}

// ---------------- 4. h = xb @ W  (bf16 MFMA, 64x64 tiles) ----------------
__global__ __launch_bounds__(256, 2) void k_gemm_h(const uint16_t* __restrict__ xb,
                                                   const uint16_t* __restrict__ wt,
                                                   uint16_t* __restrict__ h) {
  __shared__ uint16_t Xs[64][40];
  __shared__ uint16_t Ws[64][40];
  int i0 = blockIdx.x * 64;
  int f0 = blockIdx.y * 64;
  int tid = threadIdx.x;
  int w = tid >> 6, l = tid & 63;
  int q = l >> 4, r16 = l & 15;
  f32x4 acc[4];
#pragma unroll
  for (int b = 0; b < 4; b++) acc[b] = (f32x4)0.f;

  int srow = tid >> 2, sch = tid & 3;
  for (int k0 = 0; k0 < FIN; k0 += 32) {
    uint4 xv = *(const uint4*)(xb + (size_t)(i0 + srow) * FIN + k0 + sch * 8);
    uint4 wv = *(const uint4*)(wt + (size_t)(f0 + srow) * FIN + k0 + sch * 8);
    *(uint4*)(&Xs[srow][sch * 8]) = xv;
    *(uint4*)(&Ws[srow][sch * 8]) = wv;
    __syncthreads();
    s16x8 A = *(const s16x8*)(&Xs[w * 16 + r16][q * 8]);
    s16x8 B[4];
#pragma unroll
    for (int b = 0; b < 4; b++) B[b] = *(const s16x8*)(&Ws[b * 16 + r16][q * 8]);
#pragma unroll
    for (int b = 0; b < 4; b++)
      acc[b] = __builtin_amdgcn_mfma_f32_16x16x32_bf16(A, B[b], acc[b], 0, 0, 0);
    __syncthreads();
  }
#pragma unroll
  for (int b = 0; b < 4; b++)
#pragma unroll
    for (int reg = 0; reg < 4; reg++) {
      int row = i0 + w * 16 + q * 4 + reg;
      int col = f0 + b * 16 + r16;
      h[(size_t)row * FOUT + col] = f2bf(acc[b][reg]);
    }
}

// ---------------- 5. transpose h -> ht[f][j] (bf16) ----------------
__global__ __launch_bounds__(256) void k_transpose(const uint16_t* __restrict__ h,
                                                   uint16_t* __restrict__ ht) {
  __shared__ uint16_t T[64][72];
  int i0 = blockIdx.x * 64, f0 = blockIdx.y * 64;
  int tid = threadIdx.x;
#pragma unroll
  for (int p = 0; p < 2; p++) {
    int idx = tid + p * 256;
    int r = idx >> 3, c8 = idx & 7;
    uint4 v = *(const uint4*)(h + (size_t)(i0 + r) * FOUT + f0 + c8 * 8);
    *(uint4*)(&T[r][c8 * 8]) = v;
  }
  __syncthreads();
#pragma unroll
  for (int p = 0; p < 2; p++) {
    int idx = tid + p * 256;
    int fr = idx >> 3, ic8 = idx & 7;
    s16x8 v;
#pragma unroll
    for (int j = 0; j < 8; j++) v[j] = (short)T[ic8 * 8 + j][fr];
    *(s16x8*)(ht + (size_t)(f0 + fr) * NN + i0 + ic8 * 8) = v;
  }
}

// ---------------- 6. fused scores -> P(bf16) -> P @ h (MFMA), split-K ----------------
// Occupancy-first redesign: i-tile 32, JT 32 -> grid 1024 (4 blocks/CU), LDS 25.6 KB,
// VGPR capped 128 via launch_bounds(256,4) -> 16 waves/CU (4/SIMD), 2x R2, 2x R5.
// Register prefetch 1 iter ahead; wave-private Hs (no 2nd barrier); Ps dbuf + single
// no-drain barrier (lgkmcnt-only; vmcnt prefetch stays in flight).
__global__ __launch_bounds__(256, 4) void k_att(const int* __restrict__ adj,
                                                const uint16_t* __restrict__ ht,
                                                const float* __restrict__ f1,
                                                const float* __restrict__ f2,
                                                float* __restrict__ l_arr,
                                                float* __restrict__ part) {
  __shared__ uint16_t Ps[2][32][40];   // 5 KB  (double-buffered P tile, 32i x 32j)
  __shared__ uint16_t Hs[256][40];     // 20 KB (wave-private 64-row ranges, 256f x 32j)
  int i0 = blockIdx.x * IT;
  int jbase = blockIdx.y * (NN / KSPLIT);   // 2048-wide K slice
  int tid = threadIdx.x;
  int w = tid >> 6, l = tid & 63;
  int q = l >> 4, r16 = l & 15;
  int prow = tid >> 3, pch = tid & 7;       // P-compute: row prow, 4 j per thread
  int hr = l >> 2, hc = l & 3;              // Hs staging: 16 rows/pass, 4x16B chunks
  float f1i = f1[i0 + prow];
  float lsum = 0.f;

  const int*      arow = adj + (size_t)(i0 + prow) * NN + jbase + pch * 4;
  const float*    frow = f2 + jbase + pch * 4;
  const uint16_t* hrow = ht + (size_t)(w * 64 + hr) * NN + jbase + hc * 8;

  f32x4 acc[2][4];
#pragma unroll
  for (int a = 0; a < 2; a++)
#pragma unroll
    for (int b = 0; b < 4; b++) acc[a][b] = (f32x4)0.f;

  // prologue: iter-0 prefetch
  int4 adv = *(const int4*)(arow);
  f32x4 F  = *(const f32x4*)(frow);
  uint4 hv[4];
#pragma unroll
  for (int p = 0; p < 4; ++p) hv[p] = *(const uint4*)(hrow + (size_t)p * 16 * NN);

  for (int s = 0; s < NT; ++s) {
    // ---- P-compute (4 entries) from prefetched adv/F ----
    uint32_t pk0, pk1;
    {
      float p0, p1, p2, p3;
#define PC(dst, Ac, Fc) { float s_ = f1i + (Fc); float e_ = s_ > 0.f ? s_ : ALPHA * s_; \
        dst = ((Ac) != 0) ? __expf(e_) : 1.0f; lsum += dst; }
      PC(p0, adv.x, F[0]) PC(p1, adv.y, F[1]) PC(p2, adv.z, F[2]) PC(p3, adv.w, F[3])
#undef PC
      pk0 = (uint32_t)f2bf(p0) | ((uint32_t)f2bf(p1) << 16);
      pk1 = (uint32_t)f2bf(p2) | ((uint32_t)f2bf(p3) << 16);
    }
    uint16_t (*Pc)[40] = Ps[s & 1];
    uint2 pw; pw.x = pk0; pw.y = pk1;
    *(uint2*)(&Pc[prow][pch * 4]) = pw;
    // ---- Hs write (wave-private rows; hv from previous prefetch) ----
#pragma unroll
    for (int p = 0; p < 4; ++p)
      *(uint4*)(&Hs[w * 64 + p * 16 + hr][hc * 8]) = hv[p];
    // ---- issue next-iter prefetch (stays in flight across the barrier) ----
    if (s + 1 < NT) {
      int jn = (s + 1) * JT;
      adv = *(const int4*)(arow + jn);
      F   = *(const f32x4*)(frow + jn);
#pragma unroll
      for (int p = 0; p < 4; ++p) hv[p] = *(const uint4*)(hrow + (size_t)p * 16 * NN + jn);
    }
    // ---- no-drain barrier: waits LDS writes only, NOT the vmcnt prefetch ----
    asm volatile("s_waitcnt lgkmcnt(0)" ::: "memory");
    __builtin_amdgcn_s_barrier();
    asm volatile("" ::: "memory");
    // ---- MFMA phase: 8 MFMAs per wave ----
    s16x8 Af[2], Bf[4];
#pragma unroll
    for (int a = 0; a < 2; ++a) Af[a] = *(const s16x8*)(&Pc[a * 16 + r16][q * 8]);
#pragma unroll
    for (int b = 0; b < 4; ++b) Bf[b] = *(const s16x8*)(&Hs[w * 64 + b * 16 + r16][q * 8]);
#pragma unroll
    for (int a = 0; a < 2; ++a)
#pragma unroll
      for (int b = 0; b < 4; ++b)
        acc[a][b] = __builtin_amdgcn_mfma_f32_16x16x32_bf16(Af[a], Bf[b], acc[a][b], 0, 0, 0);
    // no trailing barrier: Ps double-buffered, Hs wave-private (in-wave DS ordering)
  }

  // reduce lsum over the 8 lanes sharing prow
  lsum += __shfl_down(lsum, 4);
  lsum += __shfl_down(lsum, 2);
  lsum += __shfl_down(lsum, 1);
  if (pch == 0) atomicAdd(&l_arr[i0 + prow], lsum);

  float* pb = part + (size_t)blockIdx.y * ((size_t)NN * FOUT);
#pragma unroll
  for (int a = 0; a < 2; a++)
#pragma unroll
    for (int b = 0; b < 4; b++)
#pragma unroll
      for (int reg = 0; reg < 4; reg++) {
        int row = i0 + a * 16 + q * 4 + reg;
        int col = w * 64 + b * 16 + r16;
        pb[(size_t)row * FOUT + col] = acc[a][b][reg];
      }
}

// ---------------- 7. combine split-K partials, /l, ELU, fp32 out ----------------
__global__ __launch_bounds__(256) void k_combine(const float* __restrict__ part,
                                                 const float* __restrict__ l_arr,
                                                 float* __restrict__ out) {
  int idx = (blockIdx.x * 256 + threadIdx.x) * 4;
  float r = 1.0f / l_arr[idx >> 8];
  f32x4 sum = (f32x4)0.f;
#pragma unroll
  for (int p = 0; p < KSPLIT; p++)
    sum += *(const f32x4*)(part + (size_t)p * (NN * FOUT) + idx);
  f32x4 o;
#pragma unroll
  for (int i = 0; i < 4; i++) {
    float v = sum[i] * r;
    o[i] = v > 0.f ? v : (__expf(v) - 1.f);
  }
  *(f32x4*)(out + idx) = o;
}

extern "C" void kernel_launch(void* const* d_in, const int* in_sizes, int n_in,
                              void* d_out, int out_size, void* d_ws, size_t ws_size,
                              hipStream_t stream) {
  const float* x   = (const float*)d_in[0];
  const int*   adj = (const int*)d_in[1];
  const float* W   = (const float*)d_in[2];
  const float* a   = (const float*)d_in[3];
  float* out = (float*)d_out;

  char* ws = (char*)d_ws;
  float*    wa1   = (float*)ws;                        // 512 f32
  float*    wa2   = wa1 + 512;                         // 512 f32
  float*    f1    = wa2 + 512;                         // 8192 f32
  float*    f2    = f1 + NN;                           // 8192 f32
  float*    l_arr = f2 + NN;                           // 8192 f32
  uint16_t* wt    = (uint16_t*)(l_arr + NN);           // 256*512 bf16 (256 KB)
  uint16_t* xb    = wt + (size_t)FOUT * FIN;           // 8192*512 bf16 (8 MB)
  uint16_t* h     = xb + (size_t)NN * FIN;             // 8192*256 bf16 (4 MB)
  uint16_t* ht    = h + (size_t)NN * FOUT;             // 256*8192 bf16 (4 MB)
  float*    part  = (float*)(ht + (size_t)NN * FOUT);  // KSPLIT * 8192*256 f32 (32 MB)

  k_wa<<<2, 256, 0, stream>>>(W, a, wa1, wa2);
  k_f1f2<<<NN / 4, 256, 0, stream>>>(x, wa1, wa2, f1, f2, xb, l_arr);
  k_prep_wt<<<128, 256, 0, stream>>>(W, wt);
  k_gemm_h<<<dim3(NN / 64, FOUT / 64), 256, 0, stream>>>(xb, wt, h);
  k_transpose<<<dim3(NN / 64, FOUT / 64), 256, 0, stream>>>(h, ht);
  k_att<<<dim3(NN / IT, KSPLIT), 256, 0, stream>>>(adj, ht, f1, f2, l_arr, part);
  k_combine<<<NN * FOUT / 1024, 256, 0, stream>>>(part, l_arr, out);
}

// Round 7
// 463.968 us; speedup vs baseline: 1.4707x; 1.4707x over previous
//
#include <hip/hip_runtime.h>
#include <stdint.h>

#define NN 8192
#define FIN 512
#define FOUT 256
#define ALPHA 0.2f
#define KSPLIT 8

typedef float f32x4 __attribute__((ext_vector_type(4)));
typedef short s16x8 __attribute__((ext_vector_type(8)));

__device__ __forceinline__ uint16_t f2bf(float f) {
  union { float f; uint32_t u; } v; v.f = f;
  uint32_t u = v.u + 0x7fffu + ((v.u >> 16) & 1u);
  return (uint16_t)(u >> 16);
}

// ---------------- 1. merged: wt[f][k] = bf16(W[k][f])  +  wa1/wa2 = W @ a1/a2 ----------------
__global__ __launch_bounds__(256) void k_wa_prep(const float* __restrict__ W,
                                                 const float* __restrict__ a,
                                                 uint16_t* __restrict__ wt,
                                                 float* __restrict__ wa1, float* __restrict__ wa2) {
  int bx = blockIdx.x;
  int tid = threadIdx.x;
  if (bx < 128) {
    // prep_wt part
    int idx = bx * 256 + tid;
    int f  = idx >> 7;
    int k4 = (idx & 127) * 4;
    ushort4 o;
    o.x = f2bf(W[(size_t)(k4 + 0) * FOUT + f]);
    o.y = f2bf(W[(size_t)(k4 + 1) * FOUT + f]);
    o.z = f2bf(W[(size_t)(k4 + 2) * FOUT + f]);
    o.w = f2bf(W[(size_t)(k4 + 3) * FOUT + f]);
    *(ushort4*)(wt + (size_t)f * FIN + k4) = o;
  } else {
    // wa part (2 blocks: 128, 129)
    __shared__ float a1[256], a2[256];
    a1[tid] = a[tid];
    a2[tid] = a[tid + 256];
    __syncthreads();
    int m = (bx - 128) * 256 + tid;   // 0..511
    const float* wrow = W + (size_t)m * FOUT;
    float s1 = 0.f, s2 = 0.f;
    for (int k = 0; k < FOUT; k += 4) {
      f32x4 v = *(const f32x4*)(wrow + k);
#pragma unroll
      for (int i = 0; i < 4; i++) {
        s1 += v[i] * a1[k + i];
        s2 += v[i] * a2[k + i];
      }
    }
    wa1[m] = s1; wa2[m] = s2;
  }
}

// ---------------- 2. f1/f2 = x @ wa1/wa2 + x->bf16 + l_arr zero ----------------
__global__ __launch_bounds__(256) void k_f1f2(const float* __restrict__ x,
                                              const float* __restrict__ wa1,
                                              const float* __restrict__ wa2,
                                              float* __restrict__ f1, float* __restrict__ f2,
                                              uint16_t* __restrict__ xb,
                                              float* __restrict__ l_arr) {
  __shared__ float s1[512], s2[512];
  int tid = threadIdx.x;
  if (tid < 4) l_arr[blockIdx.x * 4 + tid] = 0.f;
  s1[tid] = wa1[tid]; s1[tid + 256] = wa1[tid + 256];
  s2[tid] = wa2[tid]; s2[tid + 256] = wa2[tid + 256];
  __syncthreads();
  int w = tid >> 6, l = tid & 63;
  int row = blockIdx.x * 4 + w;
  const float* xr = x + (size_t)row * FIN + l * 8;
  f32x4 v0 = *(const f32x4*)xr;
  f32x4 v1 = *(const f32x4*)(xr + 4);
  uint4 pk;
  pk.x = (uint32_t)f2bf(v0[0]) | ((uint32_t)f2bf(v0[1]) << 16);
  pk.y = (uint32_t)f2bf(v0[2]) | ((uint32_t)f2bf(v0[3]) << 16);
  pk.z = (uint32_t)f2bf(v1[0]) | ((uint32_t)f2bf(v1[1]) << 16);
  pk.w = (uint32_t)f2bf(v1[2]) | ((uint32_t)f2bf(v1[3]) << 16);
  *(uint4*)(xb + (size_t)row * FIN + l * 8) = pk;
  int kb = l * 8;
  float d1 = 0.f, d2 = 0.f;
#pragma unroll
  for (int i = 0; i < 4; i++) {
    d1 += v0[i] * s1[kb + i] + v1[i] * s1[kb + 4 + i];
    d2 += v0[i] * s2[kb + i] + v1[i] * s2[kb + 4 + i];
  }
#pragma unroll
  for (int off = 32; off; off >>= 1) {
    d1 += __shfl_down(d1, off);
    d2 += __shfl_down(d2, off);
  }
  if (l == 0) { f1[row] = d1; f2[row] = d2; }
}

// ---------------- 3. ht[f][i] = (xb @ W)^T  -- gemm + LDS-transpose epilogue ----------------
// h itself is never consumed anywhere else, so write only the transpose.
__global__ __launch_bounds__(256, 2) void k_gemm_ht(const uint16_t* __restrict__ xb,
                                                    const uint16_t* __restrict__ wt,
                                                    uint16_t* __restrict__ ht) {
  __shared__ uint16_t Xs[64][40];
  __shared__ uint16_t Ws[64][40];
  __shared__ uint16_t T[64][72];     // transpose bounce tile (rows=i_local, cols=f_local)
  int i0 = blockIdx.x * 64;
  int f0 = blockIdx.y * 64;
  int tid = threadIdx.x;
  int w = tid >> 6, l = tid & 63;
  int q = l >> 4, r16 = l & 15;
  f32x4 acc[4];
#pragma unroll
  for (int b = 0; b < 4; b++) acc[b] = (f32x4)0.f;

  int srow = tid >> 2, sch = tid & 3;
  for (int k0 = 0; k0 < FIN; k0 += 32) {
    uint4 xv = *(const uint4*)(xb + (size_t)(i0 + srow) * FIN + k0 + sch * 8);
    uint4 wv = *(const uint4*)(wt + (size_t)(f0 + srow) * FIN + k0 + sch * 8);
    *(uint4*)(&Xs[srow][sch * 8]) = xv;
    *(uint4*)(&Ws[srow][sch * 8]) = wv;
    __syncthreads();
    s16x8 A = *(const s16x8*)(&Xs[w * 16 + r16][q * 8]);
    s16x8 B[4];
#pragma unroll
    for (int b = 0; b < 4; b++) B[b] = *(const s16x8*)(&Ws[b * 16 + r16][q * 8]);
#pragma unroll
    for (int b = 0; b < 4; b++)
      acc[b] = __builtin_amdgcn_mfma_f32_16x16x32_bf16(A, B[b], acc[b], 0, 0, 0);
    __syncthreads();
  }
  // epilogue: acc -> T (i_local x f_local), then transposed coalesced store to ht
#pragma unroll
  for (int b = 0; b < 4; b++)
#pragma unroll
    for (int reg = 0; reg < 4; reg++)
      T[w * 16 + q * 4 + reg][b * 16 + r16] = f2bf(acc[b][reg]);
  __syncthreads();
#pragma unroll
  for (int p = 0; p < 2; p++) {
    int idx = tid + p * 256;
    int fr = idx >> 3, ic8 = idx & 7;
    s16x8 v;
#pragma unroll
    for (int j = 0; j < 8; j++) v[j] = (short)T[ic8 * 8 + j][fr];
    *(s16x8*)(ht + (size_t)(f0 + fr) * NN + i0 + ic8 * 8) = v;
  }
}

// ---------------- 4. fused scores -> P(bf16) -> P @ h (MFMA), split-K ----------------
// EXACT R2 body (best measured: ~144 us at KSPLIT=4). Only change: KSPLIT=8 ->
// grid 1024 blocks (3/CU resident, LDS-limited), 16 iterations per block.
__global__ __launch_bounds__(256, 2) void k_att(const int* __restrict__ adj,
                                                const uint16_t* __restrict__ ht,
                                                const float* __restrict__ f1,
                                                const float* __restrict__ f2,
                                                float* __restrict__ l_arr,
                                                float* __restrict__ part) {
  __shared__ uint16_t Ps[64][72];    // 64 rows i x 64 j
  __shared__ uint16_t Hs[256][72];   // 256 f x 64 j
  int i0 = blockIdx.x * 64;
  int jbase = blockIdx.y * (NN / KSPLIT);   // 1024-wide K slice
  int tid = threadIdx.x;
  int w = tid >> 6, l = tid & 63;
  int q = l >> 4, r16 = l & 15;
  int prow = tid >> 2, pch = tid & 3;       // P: 16 j-elems per thread
  int srow = tid >> 3, sch = tid & 7;       // Hs staging: 8 rows x 16B per thread
  float f1i = f1[i0 + prow];
  float lsum = 0.f;
  f32x4 acc[4][4];
#pragma unroll
  for (int a = 0; a < 4; a++)
#pragma unroll
    for (int b = 0; b < 4; b++) acc[a][b] = (f32x4)0.f;

  for (int s = 0; s < NN / KSPLIT; s += 64) {
    int j0 = jbase + s;
    // 1) issue Hs staging loads (held in regs; latency hidden by P-compute below)
    uint4 hv[8];
#pragma unroll
    for (int p = 0; p < 8; p++)
      hv[p] = *(const uint4*)(ht + (size_t)(p * 32 + srow) * NN + j0 + sch * 8);
    // 2) P tile 64x64 (16 entries per thread), coalesced adj int4 loads
    const int* ap = adj + (size_t)(i0 + prow) * NN + j0 + pch * 16;
    int4 A0 = *(const int4*)ap;
    int4 A1 = *(const int4*)(ap + 4);
    int4 A2 = *(const int4*)(ap + 8);
    int4 A3 = *(const int4*)(ap + 12);
    f32x4 F0 = *(const f32x4*)(f2 + j0 + pch * 16);
    f32x4 F1 = *(const f32x4*)(f2 + j0 + pch * 16 + 4);
    f32x4 F2 = *(const f32x4*)(f2 + j0 + pch * 16 + 8);
    f32x4 F3 = *(const f32x4*)(f2 + j0 + pch * 16 + 12);
    s16x8 pv0, pv1;
#define PCOMP(dst, Ac, Fc, kk) { float s_ = f1i + (Fc); float e_ = s_ > 0.f ? s_ : ALPHA * s_; \
                                 float p_ = ((Ac) != 0) ? __expf(e_) : 1.0f; lsum += p_; \
                                 dst[kk] = (short)f2bf(p_); }
    PCOMP(pv0, A0.x, F0[0], 0); PCOMP(pv0, A0.y, F0[1], 1);
    PCOMP(pv0, A0.z, F0[2], 2); PCOMP(pv0, A0.w, F0[3], 3);
    PCOMP(pv0, A1.x, F1[0], 4); PCOMP(pv0, A1.y, F1[1], 5);
    PCOMP(pv0, A1.z, F1[2], 6); PCOMP(pv0, A1.w, F1[3], 7);
    PCOMP(pv1, A2.x, F2[0], 0); PCOMP(pv1, A2.y, F2[1], 1);
    PCOMP(pv1, A2.z, F2[2], 2); PCOMP(pv1, A2.w, F2[3], 3);
    PCOMP(pv1, A3.x, F3[0], 4); PCOMP(pv1, A3.y, F3[1], 5);
    PCOMP(pv1, A3.z, F3[2], 6); PCOMP(pv1, A3.w, F3[3], 7);
#undef PCOMP
    // 3) LDS writes
    *(s16x8*)(&Ps[prow][pch * 16]) = pv0;
    *(s16x8*)(&Ps[prow][pch * 16 + 8]) = pv1;
#pragma unroll
    for (int p = 0; p < 8; p++)
      *(uint4*)(&Hs[p * 32 + srow][sch * 8]) = hv[p];
    __syncthreads();
    // 4) two K-chunks of MFMA per barrier pair
#pragma unroll
    for (int c = 0; c < 2; c++) {
      s16x8 Af[4], Bf[4];
#pragma unroll
      for (int a = 0; a < 4; a++) Af[a] = *(const s16x8*)(&Ps[a * 16 + r16][c * 32 + q * 8]);
#pragma unroll
      for (int b = 0; b < 4; b++) Bf[b] = *(const s16x8*)(&Hs[w * 64 + b * 16 + r16][c * 32 + q * 8]);
#pragma unroll
      for (int a = 0; a < 4; a++)
#pragma unroll
        for (int b = 0; b < 4; b++)
          acc[a][b] = __builtin_amdgcn_mfma_f32_16x16x32_bf16(Af[a], Bf[b], acc[a][b], 0, 0, 0);
    }
    __syncthreads();
  }

  // reduce lsum over the 4 lanes sharing prow (lanes pch=0..3 are consecutive)
  lsum += __shfl_down(lsum, 2);
  lsum += __shfl_down(lsum, 1);
  if (pch == 0) atomicAdd(&l_arr[i0 + prow], lsum);

  float* pb = part + (size_t)blockIdx.y * ((size_t)NN * FOUT);
#pragma unroll
  for (int a = 0; a < 4; a++)
#pragma unroll
    for (int b = 0; b < 4; b++)
#pragma unroll
      for (int reg = 0; reg < 4; reg++) {
        int row = i0 + a * 16 + q * 4 + reg;
        int col = w * 64 + b * 16 + r16;
        pb[(size_t)row * FOUT + col] = acc[a][b][reg];
      }
}

// ---------------- 5. combine split-K partials, /l, ELU, fp32 out ----------------
__global__ __launch_bounds__(256) void k_combine(const float* __restrict__ part,
                                                 const float* __restrict__ l_arr,
                                                 float* __restrict__ out) {
  int idx = (blockIdx.x * 256 + threadIdx.x) * 4;
  float r = 1.0f / l_arr[idx >> 8];
  f32x4 sum = (f32x4)0.f;
#pragma unroll
  for (int p = 0; p < KSPLIT; p++)
    sum += *(const f32x4*)(part + (size_t)p * (NN * FOUT) + idx);
  f32x4 o;
#pragma unroll
  for (int i = 0; i < 4; i++) {
    float v = sum[i] * r;
    o[i] = v > 0.f ? v : (__expf(v) - 1.f);
  }
  *(f32x4*)(out + idx) = o;
}

extern "C" void kernel_launch(void* const* d_in, const int* in_sizes, int n_in,
                              void* d_out, int out_size, void* d_ws, size_t ws_size,
                              hipStream_t stream) {
  const float* x   = (const float*)d_in[0];
  const int*   adj = (const int*)d_in[1];
  const float* W   = (const float*)d_in[2];
  const float* a   = (const float*)d_in[3];
  float* out = (float*)d_out;

  char* ws = (char*)d_ws;
  float*    wa1   = (float*)ws;                        // 512 f32
  float*    wa2   = wa1 + 512;                         // 512 f32
  float*    f1    = wa2 + 512;                         // 8192 f32
  float*    f2    = f1 + NN;                           // 8192 f32
  float*    l_arr = f2 + NN;                           // 8192 f32
  uint16_t* wt    = (uint16_t*)(l_arr + NN);           // 256*512 bf16 (256 KB)
  uint16_t* xb    = wt + (size_t)FOUT * FIN;           // 8192*512 bf16 (8 MB)
  uint16_t* ht    = xb + (size_t)NN * FIN;             // 256*8192 bf16 (4 MB)
  float*    part  = (float*)(ht + (size_t)NN * FOUT);  // KSPLIT * 8192*256 f32 (64 MB)

  k_wa_prep<<<130, 256, 0, stream>>>(W, a, wt, wa1, wa2);
  k_f1f2<<<NN / 4, 256, 0, stream>>>(x, wa1, wa2, f1, f2, xb, l_arr);
  k_gemm_ht<<<dim3(NN / 64, FOUT / 64), 256, 0, stream>>>(xb, wt, ht);
  k_att<<<dim3(NN / 64, KSPLIT), 256, 0, stream>>>(adj, ht, f1, f2, l_arr, part);
  k_combine<<<NN * FOUT / 1024, 256, 0, stream>>>(part, l_arr, out);
}

// Round 8
// 437.107 us; speedup vs baseline: 1.5611x; 1.0615x over previous
//
#include <hip/hip_runtime.h>
#include <stdint.h>

#define NN 8192
#define FIN 512
#define FOUT 256
#define ALPHA 0.2f
#define KSPLIT 4

typedef float f32x4 __attribute__((ext_vector_type(4)));
typedef short s16x8 __attribute__((ext_vector_type(8)));

__device__ __forceinline__ uint16_t f2bf(float f) {
  union { float f; uint32_t u; } v; v.f = f;
  uint32_t u = v.u + 0x7fffu + ((v.u >> 16) & 1u);
  return (uint16_t)(u >> 16);
}

// ---------------- 1. merged: wt[f][k] = bf16(W[k][f])  +  wa1/wa2 = W @ a1/a2 ----------------
__global__ __launch_bounds__(256) void k_wa_prep(const float* __restrict__ W,
                                                 const float* __restrict__ a,
                                                 uint16_t* __restrict__ wt,
                                                 float* __restrict__ wa1, float* __restrict__ wa2) {
  int bx = blockIdx.x;
  int tid = threadIdx.x;
  if (bx < 128) {
    int idx = bx * 256 + tid;
    int f  = idx >> 7;
    int k4 = (idx & 127) * 4;
    ushort4 o;
    o.x = f2bf(W[(size_t)(k4 + 0) * FOUT + f]);
    o.y = f2bf(W[(size_t)(k4 + 1) * FOUT + f]);
    o.z = f2bf(W[(size_t)(k4 + 2) * FOUT + f]);
    o.w = f2bf(W[(size_t)(k4 + 3) * FOUT + f]);
    *(ushort4*)(wt + (size_t)f * FIN + k4) = o;
  } else {
    __shared__ float a1[256], a2[256];
    a1[tid] = a[tid];
    a2[tid] = a[tid + 256];
    __syncthreads();
    int m = (bx - 128) * 256 + tid;   // 0..511
    const float* wrow = W + (size_t)m * FOUT;
    float s1 = 0.f, s2 = 0.f;
    for (int k = 0; k < FOUT; k += 4) {
      f32x4 v = *(const f32x4*)(wrow + k);
#pragma unroll
      for (int i = 0; i < 4; i++) {
        s1 += v[i] * a1[k + i];
        s2 += v[i] * a2[k + i];
      }
    }
    wa1[m] = s1; wa2[m] = s2;
  }
}

// ---------------- 2. f1/f2 = x @ wa1/wa2 + x->bf16 + l_arr zero ----------------
__global__ __launch_bounds__(256) void k_f1f2(const float* __restrict__ x,
                                              const float* __restrict__ wa1,
                                              const float* __restrict__ wa2,
                                              float* __restrict__ f1, float* __restrict__ f2,
                                              uint16_t* __restrict__ xb,
                                              float* __restrict__ l_arr) {
  __shared__ float s1[512], s2[512];
  int tid = threadIdx.x;
  if (tid < 4) l_arr[blockIdx.x * 4 + tid] = 0.f;
  s1[tid] = wa1[tid]; s1[tid + 256] = wa1[tid + 256];
  s2[tid] = wa2[tid]; s2[tid + 256] = wa2[tid + 256];
  __syncthreads();
  int w = tid >> 6, l = tid & 63;
  int row = blockIdx.x * 4 + w;
  const float* xr = x + (size_t)row * FIN + l * 8;
  f32x4 v0 = *(const f32x4*)xr;
  f32x4 v1 = *(const f32x4*)(xr + 4);
  uint4 pk;
  pk.x = (uint32_t)f2bf(v0[0]) | ((uint32_t)f2bf(v0[1]) << 16);
  pk.y = (uint32_t)f2bf(v0[2]) | ((uint32_t)f2bf(v0[3]) << 16);
  pk.z = (uint32_t)f2bf(v1[0]) | ((uint32_t)f2bf(v1[1]) << 16);
  pk.w = (uint32_t)f2bf(v1[2]) | ((uint32_t)f2bf(v1[3]) << 16);
  *(uint4*)(xb + (size_t)row * FIN + l * 8) = pk;
  int kb = l * 8;
  float d1 = 0.f, d2 = 0.f;
#pragma unroll
  for (int i = 0; i < 4; i++) {
    d1 += v0[i] * s1[kb + i] + v1[i] * s1[kb + 4 + i];
    d2 += v0[i] * s2[kb + i] + v1[i] * s2[kb + 4 + i];
  }
#pragma unroll
  for (int off = 32; off; off >>= 1) {
    d1 += __shfl_down(d1, off);
    d2 += __shfl_down(d2, off);
  }
  if (l == 0) { f1[row] = d1; f2[row] = d2; }
}

// ---------------- 3. ht[f][i] = (xb @ W)^T  -- gemm + LDS-transpose epilogue ----------------
// BK=64: halves barrier count vs BK=32 (16 -> 8 K-steps).
__global__ __launch_bounds__(256, 2) void k_gemm_ht(const uint16_t* __restrict__ xb,
                                                    const uint16_t* __restrict__ wt,
                                                    uint16_t* __restrict__ ht) {
  __shared__ uint16_t Xs[64][72];
  __shared__ uint16_t Ws[64][72];
  __shared__ uint16_t T[64][72];
  int i0 = blockIdx.x * 64;
  int f0 = blockIdx.y * 64;
  int tid = threadIdx.x;
  int w = tid >> 6, l = tid & 63;
  int q = l >> 4, r16 = l & 15;
  f32x4 acc[4];
#pragma unroll
  for (int b = 0; b < 4; b++) acc[b] = (f32x4)0.f;

  int srow = tid >> 2, sch = tid & 3;   // 4 threads/row, 2 x 16B chunks each
  for (int k0 = 0; k0 < FIN; k0 += 64) {
    const uint16_t* xp = xb + (size_t)(i0 + srow) * FIN + k0;
    const uint16_t* wp = wt + (size_t)(f0 + srow) * FIN + k0;
    uint4 xv0 = *(const uint4*)(xp + sch * 8);
    uint4 xv1 = *(const uint4*)(xp + 32 + sch * 8);
    uint4 wv0 = *(const uint4*)(wp + sch * 8);
    uint4 wv1 = *(const uint4*)(wp + 32 + sch * 8);
    *(uint4*)(&Xs[srow][sch * 8]) = xv0;
    *(uint4*)(&Xs[srow][32 + sch * 8]) = xv1;
    *(uint4*)(&Ws[srow][sch * 8]) = wv0;
    *(uint4*)(&Ws[srow][32 + sch * 8]) = wv1;
    __syncthreads();
#pragma unroll
    for (int c = 0; c < 2; c++) {
      s16x8 A = *(const s16x8*)(&Xs[w * 16 + r16][c * 32 + q * 8]);
      s16x8 B[4];
#pragma unroll
      for (int b = 0; b < 4; b++) B[b] = *(const s16x8*)(&Ws[b * 16 + r16][c * 32 + q * 8]);
#pragma unroll
      for (int b = 0; b < 4; b++)
        acc[b] = __builtin_amdgcn_mfma_f32_16x16x32_bf16(A, B[b], acc[b], 0, 0, 0);
    }
    __syncthreads();
  }
  // epilogue: acc -> T (i_local x f_local), then transposed coalesced store to ht
#pragma unroll
  for (int b = 0; b < 4; b++)
#pragma unroll
    for (int reg = 0; reg < 4; reg++)
      T[w * 16 + q * 4 + reg][b * 16 + r16] = f2bf(acc[b][reg]);
  __syncthreads();
#pragma unroll
  for (int p = 0; p < 2; p++) {
    int idx = tid + p * 256;
    int fr = idx >> 3, ic8 = idx & 7;
    s16x8 v;
#pragma unroll
    for (int j = 0; j < 8; j++) v[j] = (short)T[ic8 * 8 + j][fr];
    *(s16x8*)(ht + (size_t)(f0 + fr) * NN + i0 + ic8 * 8) = v;
  }
}

// ---------------- 4. fused scores -> P(bf16) -> P @ h (MFMA), split-K ----------------
// EXACT R2 body at KSPLIT=4 (best measured config: k_att ~145 us).
__global__ __launch_bounds__(256, 2) void k_att(const int* __restrict__ adj,
                                                const uint16_t* __restrict__ ht,
                                                const float* __restrict__ f1,
                                                const float* __restrict__ f2,
                                                float* __restrict__ l_arr,
                                                float* __restrict__ part) {
  __shared__ uint16_t Ps[64][72];    // 64 rows i x 64 j
  __shared__ uint16_t Hs[256][72];   // 256 f x 64 j
  int i0 = blockIdx.x * 64;
  int jbase = blockIdx.y * (NN / KSPLIT);   // 2048-wide K slice
  int tid = threadIdx.x;
  int w = tid >> 6, l = tid & 63;
  int q = l >> 4, r16 = l & 15;
  int prow = tid >> 2, pch = tid & 3;       // P: 16 j-elems per thread
  int srow = tid >> 3, sch = tid & 7;       // Hs staging: 8 rows x 16B per thread
  float f1i = f1[i0 + prow];
  float lsum = 0.f;
  f32x4 acc[4][4];
#pragma unroll
  for (int a = 0; a < 4; a++)
#pragma unroll
    for (int b = 0; b < 4; b++) acc[a][b] = (f32x4)0.f;

  for (int s = 0; s < NN / KSPLIT; s += 64) {
    int j0 = jbase + s;
    // 1) issue Hs staging loads (held in regs; latency hidden by P-compute below)
    uint4 hv[8];
#pragma unroll
    for (int p = 0; p < 8; p++)
      hv[p] = *(const uint4*)(ht + (size_t)(p * 32 + srow) * NN + j0 + sch * 8);
    // 2) P tile 64x64 (16 entries per thread), coalesced adj int4 loads
    const int* ap = adj + (size_t)(i0 + prow) * NN + j0 + pch * 16;
    int4 A0 = *(const int4*)ap;
    int4 A1 = *(const int4*)(ap + 4);
    int4 A2 = *(const int4*)(ap + 8);
    int4 A3 = *(const int4*)(ap + 12);
    f32x4 F0 = *(const f32x4*)(f2 + j0 + pch * 16);
    f32x4 F1 = *(const f32x4*)(f2 + j0 + pch * 16 + 4);
    f32x4 F2 = *(const f32x4*)(f2 + j0 + pch * 16 + 8);
    f32x4 F3 = *(const f32x4*)(f2 + j0 + pch * 16 + 12);
    s16x8 pv0, pv1;
#define PCOMP(dst, Ac, Fc, kk) { float s_ = f1i + (Fc); float e_ = s_ > 0.f ? s_ : ALPHA * s_; \
                                 float p_ = ((Ac) != 0) ? __expf(e_) : 1.0f; lsum += p_; \
                                 dst[kk] = (short)f2bf(p_); }
    PCOMP(pv0, A0.x, F0[0], 0); PCOMP(pv0, A0.y, F0[1], 1);
    PCOMP(pv0, A0.z, F0[2], 2); PCOMP(pv0, A0.w, F0[3], 3);
    PCOMP(pv0, A1.x, F1[0], 4); PCOMP(pv0, A1.y, F1[1], 5);
    PCOMP(pv0, A1.z, F1[2], 6); PCOMP(pv0, A1.w, F1[3], 7);
    PCOMP(pv1, A2.x, F2[0], 0); PCOMP(pv1, A2.y, F2[1], 1);
    PCOMP(pv1, A2.z, F2[2], 2); PCOMP(pv1, A2.w, F2[3], 3);
    PCOMP(pv1, A3.x, F3[0], 4); PCOMP(pv1, A3.y, F3[1], 5);
    PCOMP(pv1, A3.z, F3[2], 6); PCOMP(pv1, A3.w, F3[3], 7);
#undef PCOMP
    // 3) LDS writes
    *(s16x8*)(&Ps[prow][pch * 16]) = pv0;
    *(s16x8*)(&Ps[prow][pch * 16 + 8]) = pv1;
#pragma unroll
    for (int p = 0; p < 8; p++)
      *(uint4*)(&Hs[p * 32 + srow][sch * 8]) = hv[p];
    __syncthreads();
    // 4) two K-chunks of MFMA per barrier pair
#pragma unroll
    for (int c = 0; c < 2; c++) {
      s16x8 Af[4], Bf[4];
#pragma unroll
      for (int a = 0; a < 4; a++) Af[a] = *(const s16x8*)(&Ps[a * 16 + r16][c * 32 + q * 8]);
#pragma unroll
      for (int b = 0; b < 4; b++) Bf[b] = *(const s16x8*)(&Hs[w * 64 + b * 16 + r16][c * 32 + q * 8]);
#pragma unroll
      for (int a = 0; a < 4; a++)
#pragma unroll
        for (int b = 0; b < 4; b++)
          acc[a][b] = __builtin_amdgcn_mfma_f32_16x16x32_bf16(Af[a], Bf[b], acc[a][b], 0, 0, 0);
    }
    __syncthreads();
  }

  // reduce lsum over the 4 lanes sharing prow (lanes pch=0..3 are consecutive)
  lsum += __shfl_down(lsum, 2);
  lsum += __shfl_down(lsum, 1);
  if (pch == 0) atomicAdd(&l_arr[i0 + prow], lsum);

  float* pb = part + (size_t)blockIdx.y * ((size_t)NN * FOUT);
#pragma unroll
  for (int a = 0; a < 4; a++)
#pragma unroll
    for (int b = 0; b < 4; b++)
#pragma unroll
      for (int reg = 0; reg < 4; reg++) {
        int row = i0 + a * 16 + q * 4 + reg;
        int col = w * 64 + b * 16 + r16;
        pb[(size_t)row * FOUT + col] = acc[a][b][reg];
      }
}

// ---------------- 5. combine split-K partials, /l, ELU, fp32 out ----------------
__global__ __launch_bounds__(256) void k_combine(const float* __restrict__ part,
                                                 const float* __restrict__ l_arr,
                                                 float* __restrict__ out) {
  int idx = (blockIdx.x * 256 + threadIdx.x) * 4;
  float r = 1.0f / l_arr[idx >> 8];
  f32x4 v0 = __builtin_nontemporal_load((const f32x4*)(part + 0 * (size_t)(NN * FOUT) + idx));
  f32x4 v1 = __builtin_nontemporal_load((const f32x4*)(part + 1 * (size_t)(NN * FOUT) + idx));
  f32x4 v2 = __builtin_nontemporal_load((const f32x4*)(part + 2 * (size_t)(NN * FOUT) + idx));
  f32x4 v3 = __builtin_nontemporal_load((const f32x4*)(part + 3 * (size_t)(NN * FOUT) + idx));
  f32x4 o;
#pragma unroll
  for (int i = 0; i < 4; i++) {
    float v = (v0[i] + v1[i] + v2[i] + v3[i]) * r;
    o[i] = v > 0.f ? v : (__expf(v) - 1.f);
  }
  __builtin_nontemporal_store(o, (f32x4*)(out + idx));
}

extern "C" void kernel_launch(void* const* d_in, const int* in_sizes, int n_in,
                              void* d_out, int out_size, void* d_ws, size_t ws_size,
                              hipStream_t stream) {
  const float* x   = (const float*)d_in[0];
  const int*   adj = (const int*)d_in[1];
  const float* W   = (const float*)d_in[2];
  const float* a   = (const float*)d_in[3];
  float* out = (float*)d_out;

  char* ws = (char*)d_ws;
  float*    wa1   = (float*)ws;                        // 512 f32
  float*    wa2   = wa1 + 512;                         // 512 f32
  float*    f1    = wa2 + 512;                         // 8192 f32
  float*    f2    = f1 + NN;                           // 8192 f32
  float*    l_arr = f2 + NN;                           // 8192 f32
  uint16_t* wt    = (uint16_t*)(l_arr + NN);           // 256*512 bf16 (256 KB)
  uint16_t* xb    = wt + (size_t)FOUT * FIN;           // 8192*512 bf16 (8 MB)
  uint16_t* ht    = xb + (size_t)NN * FIN;             // 256*8192 bf16 (4 MB)
  float*    part  = (float*)(ht + (size_t)NN * FOUT);  // KSPLIT * 8192*256 f32 (32 MB)

  k_wa_prep<<<130, 256, 0, stream>>>(W, a, wt, wa1, wa2);
  k_f1f2<<<NN / 4, 256, 0, stream>>>(x, wa1, wa2, f1, f2, xb, l_arr);
  k_gemm_ht<<<dim3(NN / 64, FOUT / 64), 256, 0, stream>>>(xb, wt, ht);
  k_att<<<dim3(NN / 64, KSPLIT), 256, 0, stream>>>(adj, ht, f1, f2, l_arr, part);
  k_combine<<<NN * FOUT / 1024, 256, 0, stream>>>(part, l_arr, out);
}